// Round 1
// baseline (22.484 us; speedup 1.0000x reference)
//
#include <hip/hip_runtime.h>

#define CC   512
#define CONDK 256
#define BB   8
#define TT   1024

// out[b,c] = sum_j W[c*K + j] * in[b*K + j] + bias[c]
// one wave per output row; 4 waves (4 rows) per 256-thread block; grid (C/4, B)
template<int K>
__global__ void gemv_kernel(const float* __restrict__ W, const float* __restrict__ bias,
                            const float* __restrict__ in, float* __restrict__ out) {
    const int wave = threadIdx.x >> 6;
    const int lane = threadIdx.x & 63;
    const int c = blockIdx.x * 4 + wave;
    const int b = blockIdx.y;
    const float* wrow = W + (size_t)c * K;
    const float* inb  = in + (size_t)b * K;
    float acc = 0.f;
#pragma unroll
    for (int j = lane; j < K; j += 64)
        acc += wrow[j] * inb[j];
#pragma unroll
    for (int off = 32; off >= 1; off >>= 1)
        acc += __shfl_down(acc, off, 64);
    if (lane == 0)
        out[b * CC + c] = acc + bias[c];
}

// out[b,c,t] = x[b,c,t] + w[b,c]; float4 over the contiguous t dim (1024 = 256 float4 per row)
__global__ void add_bcast_kernel(const float* __restrict__ x, const float* __restrict__ w,
                                 float* __restrict__ out) {
    const int total4 = BB * CC * TT / 4;   // 1,048,576
    const float4* x4 = (const float4*)x;
    float4* o4 = (float4*)out;
    for (int i = blockIdx.x * blockDim.x + threadIdx.x; i < total4;
         i += gridDim.x * blockDim.x) {
        const int bc = i >> 8;             // 256 float4 per (b,c) row
        const float a = w[bc];
        float4 v = x4[i];
        v.x += a; v.y += a; v.z += a; v.w += a;
        o4[i] = v;
    }
}

extern "C" void kernel_launch(void* const* d_in, const int* in_sizes, int n_in,
                              void* d_out, int out_size, void* d_ws, size_t ws_size,
                              hipStream_t stream) {
    const float* x         = (const float*)d_in[0];
    const float* cond      = (const float*)d_in[1];
    // d_in[2..7]: ln_g, ln_b, Wq, bq, Wk, bk — dead code (see analysis)
    const float* Wv        = (const float*)d_in[8];
    const float* bv        = (const float*)d_in[9];
    const float* in_proj_w = (const float*)d_in[10];
    const float* in_proj_b = (const float*)d_in[11];
    const float* out_w     = (const float*)d_in[12];
    const float* out_b     = (const float*)d_in[13];
    const float* proj_w    = (const float*)d_in[14];
    const float* proj_b    = (const float*)d_in[15];
    float* out = (float*)d_out;

    float* v1 = (float*)d_ws;          // B*C floats each
    float* v2 = v1 + BB * CC;
    float* u  = v2 + BB * CC;
    float* w  = u  + BB * CC;

    dim3 blk(256);
    dim3 g1(CC / 4, BB);
    // v-path only: wv2 = in_proj_w rows [2C, 3C), bv2 = in_proj_b[2C:]
    gemv_kernel<CONDK><<<g1, blk, 0, stream>>>(Wv, bv, cond, v1);
    gemv_kernel<CC><<<g1, blk, 0, stream>>>(in_proj_w + 2 * CC * CC, in_proj_b + 2 * CC, v1, v2);
    gemv_kernel<CC><<<g1, blk, 0, stream>>>(out_w, out_b, v2, u);
    gemv_kernel<CC><<<g1, blk, 0, stream>>>(proj_w, proj_b, u, w);

    add_bcast_kernel<<<1024, 256, 0, stream>>>(x, w, out);
}